// Round 2
// baseline (542.047 us; speedup 1.0000x reference)
//
#include <hip/hip_runtime.h>
#include <stdint.h>

#define TPB_S  512
#define EPT    8
#define EPB    (TPB_S*EPT)   // 4096 edges per scatter block
#define ABITS  11
#define APB    (1<<ABITS)    // 2048 atoms per bucket -> 8 KB LDS accumulator
#define MAXB   256           // max buckets supported by fast path
#define NSH    8             // cursor/bucket shards (contention /8)
#define TPB_A  1024          // accum block threads
#define TPB_P  512           // prep block threads

// edge energy: (r/l0)^-12 / 24 * l0 * poly_cutoff(r), p=6, r_max=6
__device__ __forceinline__ float edge_energy(float r, float l0) {
    float x = r * (1.0f / 6.0f);
    if (x >= 1.0f) return 0.0f;
    float x2 = x * x, x3 = x2 * x, x6 = x3 * x3;
    float cut = fmaf(x6, fmaf(x, fmaf(x, -21.0f, 48.0f), -28.0f), 1.0f);
    float inv = l0 / r;
    float inv2 = inv * inv, inv4 = inv2 * inv2;
    return inv4 * inv4 * inv4 * l0 * (1.0f / 24.0f) * cut;
}

// record: [29:19] local atom idx (11b), [18:0] value = fp32 bits [30:12],
// round-to-nearest at dropped 12 bits (rel err ~2.4e-4). Requires e>=0:
// cut() can round to ~-1e-6 near x->1, so clamp (true neg <=1e-14).
__device__ __forceinline__ uint32_t pack_rec(uint32_t c, float e) {
    e = fmaxf(e, 0.0f);
    uint32_t vb  = __float_as_uint(e);
    uint32_t v19 = (vb + 0x800u) >> 12;
    if (v19 > 0x7FFFFu) v19 = 0x7FFFFu;
    return ((c & (APB - 1u)) << 19) | v19;
}
__device__ __forceinline__ float unpack_val(uint32_t rec) {
    return __uint_as_float((rec & 0x7FFFFu) << 12);
}

// ---- K0: out = pae, zero cursors, detect uniform scales ------------------
__global__ __launch_bounds__(TPB_P) void k_prep(
    const float* __restrict__ scales, int tt,
    const float* __restrict__ pae, float* __restrict__ out, int N,
    uint32_t* __restrict__ cursors, uint32_t* __restrict__ uflag)
{
    int i = blockIdx.x * TPB_P + threadIdx.x;
    if (i < N) out[i] = pae[i];
    if (i < MAXB * NSH) cursors[i] = 0u;
    if (blockIdx.x == 0 && threadIdx.x == 0) {
        float v0 = scales[0];
        bool same = true;
        for (int k = 1; k < tt; ++k) same &= (__float_as_uint(scales[k]) == __float_as_uint(v0));
        uflag[0] = same ? 1u : 0u;
        uflag[1] = __float_as_uint(v0);
    }
}

// ---- K1: energy + block-local counting sort + sharded atomic slot
//          reservation + coalesced bucketed record write.
//   Phase order: the contended device atomic (cursor reservation) is issued
//   BEFORE the energy compute + LDS sort, and its result is only consumed
//   (gbase LDS store) AFTER them -> latency hidden.
__global__ __launch_bounds__(TPB_S) void k_scatter(
    const float* __restrict__ el, const int* __restrict__ ec,
    const int* __restrict__ en, const int* __restrict__ species,
    const float* __restrict__ scales, const uint32_t* __restrict__ uflag,
    uint32_t* __restrict__ cursors, uint32_t* __restrict__ bucketed,
    float* __restrict__ out, int E, int nb, int T, int cap)
{
    __shared__ uint32_t cs[EPB];      // packed records, sorted by bucket (16 KB)
    __shared__ uint8_t  bs[EPB];      // bucket of each sorted record (4 KB)
    __shared__ uint32_t hist[MAXB], lstart[MAXB], lcur[MAXB], gbase[MAXB];
    __shared__ uint32_t wsum[8];

    for (int t = threadIdx.x; t < MAXB; t += TPB_S) hist[t] = 0u;

    const uint32_t uni = uflag[0];
    const float    ul0 = __uint_as_float(uflag[1]);
    const int shard = blockIdx.x & (NSH - 1);

    const int base = blockIdx.x * EPB;
    const int i0   = base + threadIdx.x * EPT;   // 8 consecutive edges/thread

    float rr[EPT]; int cc[EPT]; int nn[EPT]; int nval = 0;

    __syncthreads();   // hist zero visible

    // ---- phase 1: load edges, bucket histogram (energies NOT yet computed)
    if (i0 + EPT <= E) {
        float4 r0 = *(const float4*)(el + i0);
        float4 r1 = *(const float4*)(el + i0 + 4);
        int4   c0 = *(const int4*)(ec + i0);
        int4   c1 = *(const int4*)(ec + i0 + 4);
        rr[0]=r0.x; rr[1]=r0.y; rr[2]=r0.z; rr[3]=r0.w;
        rr[4]=r1.x; rr[5]=r1.y; rr[6]=r1.z; rr[7]=r1.w;
        cc[0]=c0.x; cc[1]=c0.y; cc[2]=c0.z; cc[3]=c0.w;
        cc[4]=c1.x; cc[5]=c1.y; cc[6]=c1.z; cc[7]=c1.w;
        if (!uni) {
            int4 n0 = *(const int4*)(en + i0);
            int4 n1 = *(const int4*)(en + i0 + 4);
            nn[0]=n0.x; nn[1]=n0.y; nn[2]=n0.z; nn[3]=n0.w;
            nn[4]=n1.x; nn[5]=n1.y; nn[6]=n1.z; nn[7]=n1.w;
        }
        nval = EPT;
#pragma unroll
        for (int j = 0; j < EPT; ++j)
            atomicAdd(&hist[((uint32_t)cc[j]) >> ABITS], 1u);
    } else if (i0 < E) {
        nval = E - i0;
#pragma unroll
        for (int j = 0; j < EPT; ++j) {
            if (j < nval) {
                int i = i0 + j;
                cc[j] = ec[i];
                rr[j] = el[i];
                if (!uni) nn[j] = en[i];
                atomicAdd(&hist[((uint32_t)cc[j]) >> ABITS], 1u);
            }
        }
    }
    __syncthreads();

    // ---- phase 2a: wave-parallel inclusive scan of hist (256 threads)
    const int lane = threadIdx.x & 63;
    const int wv   = threadIdx.x >> 6;
    uint32_t v = 0, incl = 0;
    if (threadIdx.x < 256) {
        v = (threadIdx.x < nb) ? hist[threadIdx.x] : 0u;
        incl = v;
#pragma unroll
        for (int d = 1; d < 64; d <<= 1) {
            uint32_t t = __shfl_up(incl, d);
            if (lane >= d) incl += t;
        }
        if (lane == 63) wsum[wv] = incl;
    }
    __syncthreads();

    // ---- phase 2b: exclusive offsets + ISSUE sharded cursor atomic
    uint32_t g = 0;
    if (threadIdx.x < nb) {
        uint32_t add = 0;
        for (int k = 0; k < wv; ++k) add += wsum[k];
        uint32_t excl = incl + add - v;
        lstart[threadIdx.x] = excl;
        lcur[threadIdx.x]   = excl;
        if (v) g = atomicAdd(&cursors[shard * MAXB + threadIdx.x], v);
    }
    __syncthreads();

    // ---- phase 3: energies + pack + counting-sort into LDS
    //      (covers the in-flight cursor atomic)
    if (uni) {
#pragma unroll
        for (int j = 0; j < EPT; ++j) {
            if (j < nval) {
                uint32_t b = ((uint32_t)cc[j]) >> ABITS;
                uint32_t rec = pack_rec((uint32_t)cc[j], edge_energy(rr[j], ul0));
                uint32_t r = atomicAdd(&lcur[b], 1u);
                cs[r] = rec;
                bs[r] = (uint8_t)b;
            }
        }
    } else {
#pragma unroll
        for (int j = 0; j < EPT; ++j) {
            if (j < nval) {
                float l0 = scales[species[cc[j]] * T + species[nn[j]]];
                uint32_t b = ((uint32_t)cc[j]) >> ABITS;
                uint32_t rec = pack_rec((uint32_t)cc[j], edge_energy(rr[j], l0));
                uint32_t r = atomicAdd(&lcur[b], 1u);
                cs[r] = rec;
                bs[r] = (uint8_t)b;
            }
        }
    }
    // consume the atomic result only now (vmcnt wait sinks to here)
    if (threadIdx.x < nb) gbase[threadIdx.x] = g;
    __syncthreads();

    // ---- phase 4: coalesced write of sorted records to shard region
    const int cnt = min(EPB, E - base);
    if (cnt == EPB) {
#pragma unroll
        for (int u = 0; u < EPT; ++u) {
            int k = threadIdx.x + u * TPB_S;
            int b = bs[k];
            uint32_t rec = cs[k];
            uint32_t pib = gbase[b] + ((uint32_t)k - lstart[b]);
            if (pib < (uint32_t)cap) {
                bucketed[((size_t)b * NSH + shard) * (size_t)cap + pib] = rec;
            } else {
                int atom = (b << ABITS) | (int)(rec >> 19);
                atomicAdd(&out[atom], unpack_val(rec));   // rare overflow net
            }
        }
    } else {
        for (int k = threadIdx.x; k < cnt; k += TPB_S) {
            int b = bs[k];
            uint32_t rec = cs[k];
            uint32_t pib = gbase[b] + ((uint32_t)k - lstart[b]);
            if (pib < (uint32_t)cap) {
                bucketed[((size_t)b * NSH + shard) * (size_t)cap + pib] = rec;
            } else {
                int atom = (b << ABITS) | (int)(rec >> 19);
                atomicAdd(&out[atom], unpack_val(rec));
            }
        }
    }
}

// ---- K2: two blocks per 2048-atom bucket (4 shards each).
//   DS-pipe model (R1 counters): ds_add_f32 with divergent addresses costs
//   ~3.3 cyc/lane -> 16M LDS-atomic lanes = ~85 us/CU-saturated, invariant
//   to block count. Fix: split lane-ops 50/50 between the DS pipe (LDS acc)
//   and the L2 atomic pipe (global_atomic_add on out, fire-and-forget, no
//   return latency) so the two fixed-function units run concurrently.
__global__ __launch_bounds__(TPB_A) void k_accum_out(
    const uint32_t* __restrict__ bucketed, const uint32_t* __restrict__ cursors,
    float* __restrict__ out, int N, int cap)
{
    __shared__ float acc[APB];   // 8 KB
    const int b    = blockIdx.x >> 1;
    const int s0   = (blockIdx.x & 1) * (NSH / 2);
    const int g0   = b << ABITS;
    for (int t = threadIdx.x; t < APB; t += TPB_A) acc[t] = 0.0f;
    __syncthreads();

    for (int s = s0; s < s0 + NSH / 2; ++s) {
        uint32_t size = cursors[s * MAXB + b];
        if (size > (uint32_t)cap) size = (uint32_t)cap;
        const uint32_t* src = bucketed + ((size_t)b * NSH + s) * (size_t)cap;
        for (uint32_t k = (uint32_t)threadIdx.x * 4u; k < size; k += TPB_A * 4u) {
            if (k + 4u <= size) {
                uint4 r4 = *(const uint4*)(src + k);
                // 2 lanes -> DS pipe, 2 lanes -> L2 atomic pipe
                atomicAdd(&acc[r4.x >> 19], unpack_val(r4.x));
                atomicAdd(&acc[r4.y >> 19], unpack_val(r4.y));
                atomicAdd(&out[g0 + (int)(r4.z >> 19)], unpack_val(r4.z));
                atomicAdd(&out[g0 + (int)(r4.w >> 19)], unpack_val(r4.w));
            } else {
                for (uint32_t kk = k; kk < size; ++kk) {
                    uint32_t r = src[kk];
                    atomicAdd(&acc[r >> 19], unpack_val(r));
                }
            }
        }
    }
    __syncthreads();

    for (int l = threadIdx.x; l < APB; l += TPB_A) {
        int g = g0 + l;
        if (g < N && acc[l] != 0.0f) atomicAdd(&out[g], acc[l]);
    }
}

// ---- Fallback path (ws too small / too many buckets): device atomics ----
__global__ __launch_bounds__(256) void init_out_kernel(
    const float* __restrict__ pae, float* __restrict__ out, int N)
{
    int i = blockIdx.x * 256 + threadIdx.x;
    if (i < N) out[i] = pae[i];
}

__global__ __launch_bounds__(256) void edge_kernel_dev(
    const float* __restrict__ el, const int* __restrict__ ec,
    const int* __restrict__ en, const int* __restrict__ species,
    const float* __restrict__ scales, float* __restrict__ out, int E, int T)
{
    int i = blockIdx.x * 256 + threadIdx.x;
    if (i >= E) return;
    float r = el[i];
    int c = ec[i], n = en[i];
    float l0 = scales[species[c] * T + species[n]];
    float e = edge_energy(r, l0);
    if (e != 0.0f) atomicAdd(&out[c], e);
}

extern "C" void kernel_launch(void* const* d_in, const int* in_sizes, int n_in,
                              void* d_out, int out_size, void* d_ws, size_t ws_size,
                              hipStream_t stream) {
    const float* el      = (const float*)d_in[0];
    const int*   eidx    = (const int*)  d_in[1];   // (2,E): [0:E) center, [E:2E) neighbor
    const int*   species = (const int*)  d_in[2];
    const float* pae     = (const float*)d_in[3];
    const float* scales  = (const float*)d_in[4];
    float*       out     = (float*)d_out;

    const int E = in_sizes[0];
    const int N = in_sizes[3];
    int T = 1;
    while (T * T < in_sizes[4]) ++T;   // T = 5

    const int nb  = (N + APB - 1) / APB;           // 245 buckets
    const int nb1 = (E + EPB - 1) / EPB;           // 3907 scatter blocks
    // per-(bucket,shard) capacity: ~1.25x mean, rounded up to 1024
    const int mean_s = E / (nb * NSH);
    const int cap = (int)(((size_t)mean_s * 5 / 4 + 1023) & ~(size_t)1023);

    size_t off = 0;
    auto take = [&](size_t bytes) { size_t o = off; off += (bytes + 15) & ~(size_t)15; return o; };
    size_t o_bucketed = take((size_t)nb * NSH * (size_t)cap * 4);
    size_t o_cursors  = take((size_t)MAXB * NSH * 4);
    size_t o_uflag    = take(16);
    const size_t need = off;

    if (nb <= MAXB && ws_size >= need) {
        char* ws = (char*)d_ws;
        uint32_t* bucketed = (uint32_t*)(ws + o_bucketed);
        uint32_t* cursors  = (uint32_t*)(ws + o_cursors);
        uint32_t* uflag    = (uint32_t*)(ws + o_uflag);

        int ncov = (N > MAXB * NSH) ? N : MAXB * NSH;
        k_prep<<<(ncov + TPB_P - 1) / TPB_P, TPB_P, 0, stream>>>(
            scales, T * T, pae, out, N, cursors, uflag);
        k_scatter<<<nb1, TPB_S, 0, stream>>>(el, eidx, eidx + E, species, scales,
                                             uflag, cursors, bucketed, out,
                                             E, nb, T, cap);
        k_accum_out<<<nb * 2, TPB_A, 0, stream>>>(bucketed, cursors, out, N, cap);
    } else {
        init_out_kernel<<<(N + 255) / 256, 256, 0, stream>>>(pae, out, N);
        edge_kernel_dev<<<(E + 255) / 256, 256, 0, stream>>>(
            el, eidx, eidx + E, species, scales, out, E, T);
    }
}

// Round 3
// 251.688 us; speedup vs baseline: 2.1536x; 2.1536x over previous
//
#include <hip/hip_runtime.h>
#include <stdint.h>

#define TPB_S  512
#define EPT    8
#define EPB    (TPB_S*EPT)   // 4096 edges per scatter block
#define ABITS  10
#define APB    (1<<ABITS)    // 1024 atoms per bucket -> 4 KB LDS accumulator
#define MAXB   512           // max buckets supported by fast path
#define NSH    8             // cursor/bucket shards (contention /8)
#define TPB_A  1024          // accum block threads == APB (1 atom/thread flush)
#define TPB_P  512           // prep block threads
#define EDROP  1e-5f         // drop records with e < EDROP (max atom err ~7e-4)

// edge energy: (r/l0)^-12 / 24 * l0 * poly_cutoff(r), p=6, r_max=6
__device__ __forceinline__ float edge_energy(float r, float l0) {
    float x = r * (1.0f / 6.0f);
    if (x >= 1.0f) return 0.0f;
    float x2 = x * x, x3 = x2 * x, x6 = x3 * x3;
    float cut = fmaf(x6, fmaf(x, fmaf(x, -21.0f, 48.0f), -28.0f), 1.0f);
    float inv = l0 / r;
    float inv2 = inv * inv, inv4 = inv2 * inv2;
    return inv4 * inv4 * inv4 * l0 * (1.0f / 24.0f) * cut;
}

// record: [28:19] local atom idx (10b), [18:0] value = fp32 bits [30:12],
// round-to-nearest at dropped 12 bits (rel err ~2.4e-4). Requires e>=0.
__device__ __forceinline__ uint32_t pack_rec(uint32_t c, float e) {
    e = fmaxf(e, 0.0f);
    uint32_t vb  = __float_as_uint(e);
    uint32_t v19 = (vb + 0x800u) >> 12;
    if (v19 > 0x7FFFFu) v19 = 0x7FFFFu;
    return ((c & (APB - 1u)) << 19) | v19;
}
__device__ __forceinline__ float unpack_val(uint32_t rec) {
    return __uint_as_float((rec & 0x7FFFFu) << 12);
}

// ---- K0: out = pae, zero cursors, detect uniform scales ------------------
__global__ __launch_bounds__(TPB_P) void k_prep(
    const float* __restrict__ scales, int tt,
    const float* __restrict__ pae, float* __restrict__ out, int N,
    uint32_t* __restrict__ cursors, uint32_t* __restrict__ uflag)
{
    int i = blockIdx.x * TPB_P + threadIdx.x;
    if (i < N) out[i] = pae[i];
    if (i < MAXB * NSH) cursors[i] = 0u;
    if (blockIdx.x == 0 && threadIdx.x == 0) {
        float v0 = scales[0];
        bool same = true;
        for (int k = 1; k < tt; ++k) same &= (__float_as_uint(scales[k]) == __float_as_uint(v0));
        uflag[0] = same ? 1u : 0u;
        uflag[1] = __float_as_uint(v0);
    }
}

// ---- K1: energy + EDROP filter + block-local counting sort (merged
//   histogram/rank: one LDS atomic per KEPT record) + sharded cursor
//   reservation + coalesced bucketed write. Cursor atomic issued before the
//   cs/bs write phase, consumed after -> latency hidden. ------------------
__global__ __launch_bounds__(TPB_S) void k_scatter(
    const float* __restrict__ el, const int* __restrict__ ec,
    const int* __restrict__ en, const int* __restrict__ species,
    const float* __restrict__ scales, const uint32_t* __restrict__ uflag,
    uint32_t* __restrict__ cursors, uint32_t* __restrict__ bucketed,
    float* __restrict__ out, int E, int nb, int T, int cap)
{
    __shared__ uint32_t cs[EPB];      // packed records, sorted by bucket (16 KB)
    __shared__ uint16_t bs[EPB];      // bucket of each sorted record (8 KB)
    __shared__ uint32_t cnt[MAXB], lstart[MAXB], gbase[MAXB];  // 6 KB
    __shared__ uint32_t wsum[8];

    for (int t = threadIdx.x; t < MAXB; t += TPB_S) cnt[t] = 0u;

    const uint32_t uni = uflag[0];
    const float    ul0 = __uint_as_float(uflag[1]);
    const int shard = blockIdx.x & (NSH - 1);

    const int base = blockIdx.x * EPB;
    const int i0   = base + threadIdx.x * EPT;   // 8 consecutive edges/thread

    uint32_t recs[EPT]; int bkt[EPT]; uint32_t rnk[EPT];
#pragma unroll
    for (int j = 0; j < EPT; ++j) rnk[j] = 0xFFFFFFFFu;

    __syncthreads();   // cnt zero visible

    // ---- phase 1: load edges, energies, EDROP filter, rank reservation
    if (i0 + EPT <= E) {
        float4 r0 = *(const float4*)(el + i0);
        float4 r1 = *(const float4*)(el + i0 + 4);
        int4   c0 = *(const int4*)(ec + i0);
        int4   c1 = *(const int4*)(ec + i0 + 4);
        float rr[EPT] = {r0.x,r0.y,r0.z,r0.w, r1.x,r1.y,r1.z,r1.w};
        int   cc[EPT] = {c0.x,c0.y,c0.z,c0.w, c1.x,c1.y,c1.z,c1.w};
        if (uni) {
#pragma unroll
            for (int j = 0; j < EPT; ++j) {
                float e = edge_energy(rr[j], ul0);
                if (e >= EDROP) {
                    recs[j] = pack_rec((uint32_t)cc[j], e);
                    bkt[j]  = (int)((uint32_t)cc[j] >> ABITS);
                    rnk[j]  = atomicAdd(&cnt[bkt[j]], 1u);
                }
            }
        } else {
            int4 n0 = *(const int4*)(en + i0);
            int4 n1 = *(const int4*)(en + i0 + 4);
            int  nn[EPT] = {n0.x,n0.y,n0.z,n0.w, n1.x,n1.y,n1.z,n1.w};
#pragma unroll
            for (int j = 0; j < EPT; ++j) {
                float l0 = scales[species[cc[j]] * T + species[nn[j]]];
                float e = edge_energy(rr[j], l0);
                if (e >= EDROP) {
                    recs[j] = pack_rec((uint32_t)cc[j], e);
                    bkt[j]  = (int)((uint32_t)cc[j] >> ABITS);
                    rnk[j]  = atomicAdd(&cnt[bkt[j]], 1u);
                }
            }
        }
    } else if (i0 < E) {
        int nval = E - i0;
#pragma unroll
        for (int j = 0; j < EPT; ++j) {
            if (j < nval) {
                int i = i0 + j;
                int c = ec[i];
                float l0 = uni ? ul0 : scales[species[c] * T + species[en[i]]];
                float e = edge_energy(el[i], l0);
                if (e >= EDROP) {
                    recs[j] = pack_rec((uint32_t)c, e);
                    bkt[j]  = (int)((uint32_t)c >> ABITS);
                    rnk[j]  = atomicAdd(&cnt[bkt[j]], 1u);
                }
            }
        }
    }
    __syncthreads();

    // ---- phase 2a: wave-parallel inclusive scan of cnt (512 threads)
    const int lane = threadIdx.x & 63;
    const int wv   = threadIdx.x >> 6;
    uint32_t v = (threadIdx.x < nb) ? cnt[threadIdx.x] : 0u;
    uint32_t incl = v;
#pragma unroll
    for (int d = 1; d < 64; d <<= 1) {
        uint32_t t = __shfl_up(incl, d);
        if (lane >= d) incl += t;
    }
    if (lane == 63) wsum[wv] = incl;
    __syncthreads();

    // ---- phase 2b: exclusive offsets + ISSUE sharded cursor atomic
    uint32_t g = 0;
    {
        uint32_t add = 0;
        for (int k = 0; k < wv; ++k) add += wsum[k];
        uint32_t excl = incl + add - v;
        if (threadIdx.x < nb) {
            lstart[threadIdx.x] = excl;
            if (v) g = atomicAdd(&cursors[shard * MAXB + threadIdx.x], v);
        }
    }
    __syncthreads();

    // ---- phase 3: scatter kept records into cs/bs (covers cursor atomic)
#pragma unroll
    for (int j = 0; j < EPT; ++j) {
        if (rnk[j] != 0xFFFFFFFFu) {
            uint32_t r = lstart[bkt[j]] + rnk[j];
            cs[r] = recs[j];
            bs[r] = (uint16_t)bkt[j];
        }
    }
    // consume the atomic result only now (vmcnt wait sinks to here)
    if (threadIdx.x < nb) gbase[threadIdx.x] = g;
    __syncthreads();

    // ---- phase 4: coalesced write of sorted records to shard regions
    uint32_t tot = wsum[0] + wsum[1] + wsum[2] + wsum[3]
                 + wsum[4] + wsum[5] + wsum[6] + wsum[7];
    for (uint32_t k = threadIdx.x; k < tot; k += TPB_S) {
        int b = bs[k];
        uint32_t rec = cs[k];
        uint32_t pib = gbase[b] + (k - lstart[b]);
        if (pib < (uint32_t)cap) {
            bucketed[((size_t)b * NSH + shard) * (size_t)cap + pib] = rec;
        } else {
            // capacity overflow safety net (expected ~0 hits)
            int atom = (b << ABITS) | (int)(rec >> 19);
            atomicAdd(&out[atom], unpack_val(rec));
        }
    }
}

// ---- K2: one block per 1024-atom bucket, all 8 shards: LDS-atomic
//   accumulate (DS pipe), then ATOMIC-FREE flush: thread t owns atom t,
//   plain out[g] += acc[t] (out = pae + rare spills; single writer;
//   stream-ordered after k_scatter). No global atomics on the hot path. ---
__global__ __launch_bounds__(TPB_A) void k_accum_out(
    const uint32_t* __restrict__ bucketed, const uint32_t* __restrict__ cursors,
    float* __restrict__ out, int N, int cap)
{
    __shared__ float acc[APB];   // 4 KB
    const int b = blockIdx.x;
    acc[threadIdx.x] = 0.0f;     // TPB_A == APB
    __syncthreads();

    for (int s = 0; s < NSH; ++s) {
        uint32_t size = cursors[s * MAXB + b];
        if (size > (uint32_t)cap) size = (uint32_t)cap;
        const uint32_t* src = bucketed + ((size_t)b * NSH + s) * (size_t)cap;
        for (uint32_t k = (uint32_t)threadIdx.x * 4u; k < size; k += TPB_A * 4u) {
            if (k + 4u <= size) {
                uint4 r4 = *(const uint4*)(src + k);
                atomicAdd(&acc[r4.x >> 19], unpack_val(r4.x));
                atomicAdd(&acc[r4.y >> 19], unpack_val(r4.y));
                atomicAdd(&acc[r4.z >> 19], unpack_val(r4.z));
                atomicAdd(&acc[r4.w >> 19], unpack_val(r4.w));
            } else {
                for (uint32_t kk = k; kk < size; ++kk) {
                    uint32_t r = src[kk];
                    atomicAdd(&acc[r >> 19], unpack_val(r));
                }
            }
        }
    }
    __syncthreads();

    int g = (b << ABITS) + threadIdx.x;
    float a = acc[threadIdx.x];
    if (g < N && a != 0.0f) out[g] += a;
}

// ---- Fallback path (ws too small / too many buckets): device atomics ----
__global__ __launch_bounds__(256) void init_out_kernel(
    const float* __restrict__ pae, float* __restrict__ out, int N)
{
    int i = blockIdx.x * 256 + threadIdx.x;
    if (i < N) out[i] = pae[i];
}

__global__ __launch_bounds__(256) void edge_kernel_dev(
    const float* __restrict__ el, const int* __restrict__ ec,
    const int* __restrict__ en, const int* __restrict__ species,
    const float* __restrict__ scales, float* __restrict__ out, int E, int T)
{
    int i = blockIdx.x * 256 + threadIdx.x;
    if (i >= E) return;
    float r = el[i];
    int c = ec[i], n = en[i];
    float l0 = scales[species[c] * T + species[n]];
    float e = edge_energy(r, l0);
    if (e >= EDROP) atomicAdd(&out[c], e);
}

extern "C" void kernel_launch(void* const* d_in, const int* in_sizes, int n_in,
                              void* d_out, int out_size, void* d_ws, size_t ws_size,
                              hipStream_t stream) {
    const float* el      = (const float*)d_in[0];
    const int*   eidx    = (const int*)  d_in[1];   // (2,E): [0:E) center, [E:2E) neighbor
    const int*   species = (const int*)  d_in[2];
    const float* pae     = (const float*)d_in[3];
    const float* scales  = (const float*)d_in[4];
    float*       out     = (float*)d_out;

    const int E = in_sizes[0];
    const int N = in_sizes[3];
    int T = 1;
    while (T * T < in_sizes[4]) ++T;   // T = 5

    const int nb  = (N + APB - 1) / APB;           // 489 buckets
    const int nb1 = (E + EPB - 1) / EPB;           // 3907 scatter blocks
    // per-(bucket,shard) capacity: ~1.125x full-E mean (16 sigma), 1024-align
    const int mean_s = E / (nb * NSH);
    const int cap = (int)(((size_t)mean_s * 9 / 8 + 1023) & ~(size_t)1023);

    size_t off = 0;
    auto take = [&](size_t bytes) { size_t o = off; off += (bytes + 15) & ~(size_t)15; return o; };
    size_t o_bucketed = take((size_t)nb * NSH * (size_t)cap * 4);
    size_t o_cursors  = take((size_t)MAXB * NSH * 4);
    size_t o_uflag    = take(16);
    const size_t need = off;

    if (nb <= MAXB && ws_size >= need) {
        char* ws = (char*)d_ws;
        uint32_t* bucketed = (uint32_t*)(ws + o_bucketed);
        uint32_t* cursors  = (uint32_t*)(ws + o_cursors);
        uint32_t* uflag    = (uint32_t*)(ws + o_uflag);

        int ncov = (N > MAXB * NSH) ? N : MAXB * NSH;
        k_prep<<<(ncov + TPB_P - 1) / TPB_P, TPB_P, 0, stream>>>(
            scales, T * T, pae, out, N, cursors, uflag);
        k_scatter<<<nb1, TPB_S, 0, stream>>>(el, eidx, eidx + E, species, scales,
                                             uflag, cursors, bucketed, out,
                                             E, nb, T, cap);
        k_accum_out<<<nb, TPB_A, 0, stream>>>(bucketed, cursors, out, N, cap);
    } else {
        init_out_kernel<<<(N + 255) / 256, 256, 0, stream>>>(pae, out, N);
        edge_kernel_dev<<<(E + 255) / 256, 256, 0, stream>>>(
            el, eidx, eidx + E, species, scales, out, E, T);
    }
}